// Round 2
// baseline (412.541 us; speedup 1.0000x reference)
//
#include <hip/hip_runtime.h>

// MXFP8 E4M3 quantize-dequantize (microxcaling semantics), fp32 -> fp32.
// BLOCK_SIZE=32 along last axis, EMAX=8, MBITS=5 (3 mantissa bits), MAX_NORM=448,
// scale clamp at 2^-127, denorm private exponents clamped at -6.
//
// Exactness: all reference float ops are multiplies/divides by powers of two
// plus a round-half-away-from-zero in [0,16) and a clip — all bit-exact in
// fp32 when implemented with ldexpf + exponent-field extraction.
//  - floor(log2(x)) for normal x>0 == biased exponent - 127.
//  - For denormal/zero amax the bit-trick yields -127, true floor is <= -135;
//    both clamp to shared_exp = -127 -> identical.
//  - For denormal/zero a the bit-trick yields pe = -127, true floor <= -127;
//    both clamp to pe = -6 -> identical (and a==0 quantizes to 0 either way).

__device__ __forceinline__ float mx_quant_elem(float x, int sh) {
    // a = x / 2^sh  (exact: power-of-two scale)
    float a = ldexpf(x, -sh);
    // private exponent: floor(log2(|a|)), clamped to MIN_EXP = -6
    int pe = (int)((__float_as_uint(a) >> 23) & 0xFFu) - 127;
    pe = (pe < -6) ? -6 : pe;
    // put mantissa bits (MBITS-2 = 3) into the integer part: v = a * 2^(3-pe)
    float v = ldexpf(a, 3 - pe);
    // round to nearest, half away from zero (|v| < 16 so +0.5/floor are exact)
    float r = copysignf(floorf(fabsf(v) + 0.5f), v);
    // back to block-scaled domain
    float q = ldexpf(r, pe - 3);
    // saturate to e4m3 max normal
    q = fminf(fmaxf(q, -448.0f), 448.0f);
    // dequantize
    return ldexpf(q, sh);
}

__global__ __launch_bounds__(256) void mx_quantize_kernel(
        const float4* __restrict__ in, float4* __restrict__ out, int n4) {
    int stride = gridDim.x * blockDim.x;
    for (int tid = blockIdx.x * blockDim.x + threadIdx.x; tid < n4; tid += stride) {
        float4 d = in[tid];

        // block amax: 4 elems local, then reduce across the 8 lanes that share
        // one 32-element MX block (shfl_xor masks 1,2,4 stay inside the group)
        float m = fmaxf(fmaxf(fabsf(d.x), fabsf(d.y)), fmaxf(fabsf(d.z), fabsf(d.w)));
        m = fmaxf(m, __shfl_xor(m, 1, 64));
        m = fmaxf(m, __shfl_xor(m, 2, 64));
        m = fmaxf(m, __shfl_xor(m, 4, 64));

        // shared exponent: floor(log2(amax)) - EMAX, clamped to >= -127.
        // (amax >= 0 so sign bit is 0; exponent field alone suffices)
        int fl = (int)(__float_as_uint(m) >> 23) - 127;
        int sh = fl - 8;
        sh = (sh < -127) ? -127 : sh;
        // overflow->NaN branch (shared_exp > 127) is unreachable for finite
        // fp32 inputs: fl <= 127 => sh <= 119.

        d.x = mx_quant_elem(d.x, sh);
        d.y = mx_quant_elem(d.y, sh);
        d.z = mx_quant_elem(d.z, sh);
        d.w = mx_quant_elem(d.w, sh);

        out[tid] = d;
    }
}

extern "C" void kernel_launch(void* const* d_in, const int* in_sizes, int n_in,
                              void* d_out, int out_size, void* d_ws, size_t ws_size,
                              hipStream_t stream) {
    const float4* in = (const float4*)d_in[0];
    float4* out = (float4*)d_out;
    int n4 = in_sizes[0] / 4;   // 8192*8192/4 = 16,777,216 work items
    int block = 256;
    int grid = (n4 + block - 1) / block;   // 65,536 blocks
    mx_quantize_kernel<<<grid, block, 0, stream>>>(in, out, n4);
}

// Round 4
// 406.867 us; speedup vs baseline: 1.0139x; 1.0139x over previous
//
#include <hip/hip_runtime.h>

// MXFP8 E4M3 quantize-dequantize (microxcaling semantics), fp32 -> fp32.
// BLOCK_SIZE=32 along last axis, EMAX=8, MBITS=5 (3 mantissa bits), MAX_NORM=448.
// Bit-exact vs reference: floor(log2) via exponent-field extraction (clamps
// make denorm/zero cases coincide), power-of-two scales via v_ldexp_f32
// (exact), round-half-away-from-zero via floor(|v|+0.5) with |v|<16 (exact).
//
// R3: fix compile — DPP ctrl as template immediate; nontemporal via clang
// ext_vector_type float4 (HIP_vector_type not accepted by the builtin).

typedef float vfloat4 __attribute__((ext_vector_type(4)));

template <int CTRL>
__device__ __forceinline__ float dpp_max(float x) {
    int partner = __builtin_amdgcn_update_dpp(
        0, __float_as_int(x), CTRL, 0xF, 0xF, true);
    return fmaxf(x, __int_as_float(partner));
}

__device__ __forceinline__ float mx_quant_elem(float x, int sh) {
    // a = x / 2^sh  (exact: power-of-two scale)
    float a = ldexpf(x, -sh);
    // private exponent: floor(log2(|a|)), clamped to MIN_EXP = -6
    int pe = (int)((__float_as_uint(a) >> 23) & 0xFFu) - 127;
    pe = (pe < -6) ? -6 : pe;
    // put the 3 mantissa bits into the integer part: v = a * 2^(3-pe)
    float v = ldexpf(a, 3 - pe);
    // round to nearest, half away from zero (|v| < 16 so +0.5/floor exact)
    float r = copysignf(floorf(fabsf(v) + 0.5f), v);
    // back to block-scaled domain, saturate to e4m3 max normal, dequantize
    float q = ldexpf(r, pe - 3);
    q = fminf(fmaxf(q, -448.0f), 448.0f);
    return ldexpf(q, sh);
}

__global__ __launch_bounds__(256) void mx_quantize_kernel(
        const vfloat4* __restrict__ in, vfloat4* __restrict__ out, int n4) {
    int stride = gridDim.x * blockDim.x;
    for (int tid = blockIdx.x * blockDim.x + threadIdx.x; tid < n4; tid += stride) {
        vfloat4 d = __builtin_nontemporal_load(&in[tid]);

        // 32-elem MX block = 8 consecutive lanes x float4.
        // Lane-local amax, then 8-lane max via 3 DPP ops (all-VALU):
        //   0xB1 = quad_perm [1,0,3,2]  (xor 1)
        //   0x4E = quad_perm [2,3,0,1]  (xor 2)
        //   0x141 = row_half_mirror     (xor 7 -> crosses the two quads;
        //           valid because each lane already holds its quad-max)
        float m = fmaxf(fmaxf(fabsf(d.x), fabsf(d.y)), fmaxf(fabsf(d.z), fabsf(d.w)));
        m = dpp_max<0xB1>(m);
        m = dpp_max<0x4E>(m);
        m = dpp_max<0x141>(m);

        // shared exponent: floor(log2(amax)) - EMAX, clamped to >= -127.
        // (m >= 0 so the exponent field alone suffices; amax==0 -> fl=-127,
        // matching the reference's clamp path.)
        int fl = (int)(__float_as_uint(m) >> 23) - 127;
        int sh = fl - 8;
        sh = (sh < -127) ? -127 : sh;
        // overflow->NaN branch (shared_exp > 127) unreachable for finite fp32.

        d.x = mx_quant_elem(d.x, sh);
        d.y = mx_quant_elem(d.y, sh);
        d.z = mx_quant_elem(d.z, sh);
        d.w = mx_quant_elem(d.w, sh);

        __builtin_nontemporal_store(d, &out[tid]);
    }
}

extern "C" void kernel_launch(void* const* d_in, const int* in_sizes, int n_in,
                              void* d_out, int out_size, void* d_ws, size_t ws_size,
                              hipStream_t stream) {
    const vfloat4* in = (const vfloat4*)d_in[0];
    vfloat4* out = (vfloat4*)d_out;
    int n4 = in_sizes[0] / 4;   // 16,777,216 float4 work items
    int block = 256;
    int grid = (n4 + block - 1) / block;   // 65,536 blocks
    mx_quantize_kernel<<<grid, block, 0, stream>>>(in, out, n4);
}